// Round 11
// baseline (341.787 us; speedup 1.0000x reference)
//
#include <hip/hip_runtime.h>
#include <math.h>

#define B_    2
#define L_    2048
#define D_    768
#define K_    12
#define KQ_   6
#define M_    4
#define H_    64
#define ZC_   780      // MEM + K
#define NTOK_ 4096     // B*L
#define NC_   64       // scan chunks per batch
#define LC_   32       // chunk length (L/NC)
#define QST_  3072     // q fp16 row stride
#define XPN_  4224     // merged projection N: 3328 (q+skd+pad) + 896 (wmem)

typedef __attribute__((ext_vector_type(8))) _Float16 half8;
typedef __attribute__((ext_vector_type(4))) float f32x4;

__device__ __forceinline__ float softplus_f(float x) {
  return (x > 20.f) ? x : log1pf(expf(x));
}

__device__ __forceinline__ float fast_tanh(float x) {
  float xx = fminf(fmaxf(x, -10.f), 10.f);
  float e = __expf(2.f * xx);
  return (e - 1.f) / (e + 1.f);
}

// async global->LDS 16B per lane (dest = wave-uniform base + lane*16)
__device__ __forceinline__ void async16(const _Float16* g, _Float16* l) {
  __builtin_amdgcn_global_load_lds(
      (const __attribute__((address_space(1))) unsigned int*)g,
      (__attribute__((address_space(3))) unsigned int*)l, 16, 0, 0);
}

// val/gate 16-interleave permutation for spec-B columns
__device__ __forceinline__ int permcol(int n) {
  int isg = (n >= 192) ? 1 : 0;
  int j = n - 192 * isg;
  return (j >> 4) * 32 + (isg << 4) + (j & 15);
}

// ---------------------------------------------------------------------------
// Transpose+convert body; optional perm + scale
// ---------------------------------------------------------------------------
__device__ __forceinline__ void cvt_t_body(float (*tile)[33], int bx, int by, int kz,
                                           const float* src, long sKs, int srs,
                                           _Float16* dh, long dKs, int dst, int doff,
                                           int R, int Nact, bool perm, float scale) {
  const float* s = src + (size_t)kz * sKs;
  _Float16* dhh = dh + (size_t)kz * dKs;
  const int kb = bx * 32;
  const int nb = by * 32;
  const int tx = threadIdx.x & 31, ty = threadIdx.x >> 5;
  for (int i = ty; i < 32; i += 8) {
    int kk = kb + i, n = nb + tx;
    tile[i][tx] = (kk < R && n < Nact) ? s[(size_t)kk * srs + n] : 0.f;
  }
  __syncthreads();
  for (int i = ty; i < 32; i += 8) {
    int n = nb + i, kk = kb + tx;
    if (kk < R) {
      float v = tile[tx][i] * scale;
      int dn = perm ? permcol(n) : n;
      dhh[(size_t)dn * dst + doff + kk] = (_Float16)v;
    }
  }
}

// ---------------------------------------------------------------------------
// Merged prep: weight conversion + out-zero + x->fp16 + precomp tables.
// xpb layout (rows x 768): [W_q^T 0:3072 | skd^T 3072:3264 | pad | W_mem^T 3328:4108]
// ---------------------------------------------------------------------------
__global__ void prep_kernel(const float* __restrict__ x, float* __restrict__ out,
                            const float* __restrict__ theta_d_raw,
                            const float* __restrict__ decay,
                            float* __restrict__ theta_tab, float* __restrict__ w_tab,
                            float* __restrict__ slopes_sp,
                            const float* __restrict__ W_mem, const float* __restrict__ W_q,
                            const float* __restrict__ skip_down_W, const float* __restrict__ out_W,
                            const float* __restrict__ W_re, const float* __restrict__ W_im,
                            const float* __restrict__ skip_up_W, const float* __restrict__ hs,
                            _Float16* __restrict__ x_h, _Float16* __restrict__ xpb_h,
                            _Float16* __restrict__ outw_h, _Float16* __restrict__ bsp_h) {
  __shared__ float tile[32][33];
  int b = blockIdx.x;
  if (b < 672) {           // W_mem -> xpb rows [3328,4108), 24x28
    cvt_t_body(tile, b % 24, b / 24, 0, W_mem, 0, ZC_, xpb_h + (size_t)3328 * 768,
               0, 768, 0, 768, ZC_, false, 1.f);
    return;
  }
  b -= 672;
  if (b < 2304) {          // W_q -> xpb rows [0,3072), 24x96
    cvt_t_body(tile, b % 24, b / 24, 0, W_q, 0, 3072, xpb_h, 0, 768, 0, 768, 3072, false, 1.f);
    return;
  }
  b -= 2304;
  if (b < 192) {           // skip_down -> xpb rows [3072,3264), 24x8
    cvt_t_body(tile, b % 24, b / 24, 0, skip_down_W, 0, 192, xpb_h + (size_t)3072 * 768,
               0, 768, 0, 768, 192, false, 1.f);
    return;
  }
  b -= 192;
  if (b < 1728) {          // out_W -> outw, 72x24
    cvt_t_body(tile, b % 72, b / 72, 0, out_W, 0, 768, outw_h, 0, 2304, 0, 2304, 768, false, 1.f);
    return;
  }
  b -= 1728;
  if (b < 288) {           // W_re -> bsp[k][perm(n)][0:64], 2x12x12
    cvt_t_body(tile, b % 2, (b / 2) % 12, b / 24, W_re, 64L * 384, 384, bsp_h,
               384L * 320, 320, 0, 64, 384, true, 1.f);
    return;
  }
  b -= 288;
  if (b < 288) {           // W_im -> bsp[k][perm(n)][64:128]
    cvt_t_body(tile, b % 2, (b / 2) % 12, b / 24, W_im, 64L * 384, 384, bsp_h,
               384L * 320, 320, 64, 64, 384, true, 1.f);
    return;
  }
  b -= 288;
  if (b < 864) {           // skip_up slice -> bsp[k][perm(n)][128:320] * hs[k], 6x12x12
    int kz = b / 72;
    cvt_t_body(tile, b % 6, (b / 6) % 12, kz, skip_up_W, 384, 4608, bsp_h,
               384L * 320, 320, 128, 192, 384, true, hs[kz]);
    return;
  }
  b -= 864;
  if (b < 12288) {         // zero out (4096*768 = 12288*256 exactly)
    out[(size_t)b * 256 + threadIdx.x] = 0.f;
    return;
  }
  b -= 12288;
  if (b < 12288) {         // x -> fp16
    size_t i = (size_t)b * 256 + threadIdx.x;
    x_h[i] = (_Float16)x[i];
    return;
  }
  b -= 12288;
  // precomp tables (3 blocks)
  int idx = b * 256 + threadIdx.x;
  if (idx < K_) slopes_sp[idx] = softplus_f(decay[idx]);
  if (idx >= K_ * H_) return;
  float td[M_], ta[M_];
#pragma unroll
  for (int m = 0; m < M_; ++m) td[m] = softplus_f(theta_d_raw[idx * M_ + m]) + 1e-4f;
  ta[0] = td[0];
#pragma unroll
  for (int m = 1; m < M_; ++m) ta[m] = ta[m - 1] + td[m];
  float total = ta[M_ - 1];
  float rs = 2.999f / total;
#pragma unroll
  for (int m = 0; m < M_; ++m) theta_tab[idx * M_ + m] = 0.001f + ta[m] * rs;
  float d0 = (ta[1] - ta[0]) * rs;
  float d1 = (ta[2] - ta[1]) * rs;
  float d2 = (ta[3] - ta[2]) * rs;
  w_tab[idx * M_ + 0] = 0.5f * d0;
  w_tab[idx * M_ + 1] = 0.5f * (d0 + d1);
  w_tab[idx * M_ + 2] = 0.5f * (d1 + d2);
  w_tab[idx * M_ + 3] = 0.5f * d2;
}

// ---------------------------------------------------------------------------
__global__ __launch_bounds__(256) void gate_kernel(const float* __restrict__ x,
                                                   const float* __restrict__ gW,
                                                   float* __restrict__ gatelin) {
  __shared__ float gws[768 * 12];
  for (int i = threadIdx.x; i < 768 * 12; i += 256) gws[i] = gW[i];
  __syncthreads();
  const int wave = threadIdx.x >> 6, lane = threadIdx.x & 63;
  const int t = blockIdx.x * 4 + wave;
  const float* xt = x + (size_t)t * D_;
  float acc[12];
#pragma unroll
  for (int k = 0; k < 12; ++k) acc[k] = 0.f;
#pragma unroll
  for (int i = 0; i < 12; ++i) {
    float xv = xt[lane + 64 * i];
    const float* w = &gws[(lane + 64 * i) * 12];
#pragma unroll
    for (int k = 0; k < 12; ++k) acc[k] += xv * w[k];
  }
#pragma unroll
  for (int k = 0; k < 12; ++k) {
    acc[k] += __shfl_xor(acc[k], 32);
    acc[k] += __shfl_xor(acc[k], 16);
    acc[k] += __shfl_xor(acc[k], 8);
    acc[k] += __shfl_xor(acc[k], 4);
    acc[k] += __shfl_xor(acc[k], 2);
    acc[k] += __shfl_xor(acc[k], 1);
  }
  if (lane < 12) {
    float v = 0.f;
#pragma unroll
    for (int k = 0; k < 12; ++k)
      if (lane == k) v = acc[k];
    gatelin[(size_t)t * K_ + lane] = v;
  }
}

// ---------------------------------------------------------------------------
// MFMA fp16 GEMM: dbuf LDS, raw barriers + fine vmcnt, XOR(row>>1) swizzle,
// XCD-aware 1D grid (yz-fastest: consecutive blocks on one XCD share B-tile,
// pinned A-slices stay in that XCD's L2).
// EPI=0: f32 store (ATOMIC: zz = K-split, atomicAdd into zeroed C).
// EPI=1: spec GEMM (zz = batch k): A split source (Ah per-k 128-stride k<128,
//        A2 shared 192-stride k>=128); fused val/gate SiLU -> YH.
// EPI=2: merged x-projection: col<3072 -> QH fp16 (q); [3072,3264) -> YH fp16
//        (lat); [3328,3328+780) -> (fp16)C (z); else skip.
// ---------------------------------------------------------------------------
template <int ATOMIC, int EPI>
__global__ __launch_bounds__(256)
void mfma_gemm_kernel(const _Float16* __restrict__ Ah, const _Float16* __restrict__ Bh,
                      float* __restrict__ C,
                      int Kd, int Nact,
                      long strideA, long strideB, long strideC,
                      const _Float16* __restrict__ A2, _Float16* __restrict__ YH,
                      _Float16* __restrict__ QH, int gy, int nsplit) {
  __shared__ __align__(16) _Float16 sA[2][128 * 32];
  __shared__ __align__(16) _Float16 sB[2][128 * 32];
  int bx, by, kz, kbeg, kend;
  {
    int bid = blockIdx.x;
    int xcd = bid & 7, s = bid >> 3;
    int nyz = (gy * nsplit) >> 3;
    int yz = s % nyz;          // fastest: same bx shares B-tile on this XCD
    bx = s / nyz;
    int p = xcd + 8 * yz;
    by = p % gy;
    int zz = p / gy;
    if (ATOMIC) {
      kz = 0;
      int len = Kd / nsplit;
      kbeg = zz * len;
      kend = kbeg + len;
    } else {
      kz = zz;
      kbeg = 0;
      kend = Kd;
    }
  }
  const _Float16* A0 = Ah + (size_t)kz * strideA;
  const _Float16* B0 = Bh + (size_t)kz * strideB;
  float* Cb = C + (size_t)kz * strideC;
  const int bm0 = by * 128;
  const int bn0 = bx * 128;
  const int tid = threadIdx.x;
  const int wave = tid >> 6, lane = tid & 63;
  const int m16 = lane & 15, quad = lane >> 4;
  const int wr = (wave & 1) * 64, wc = (wave >> 1) * 64;

  f32x4 acc[4][4];
#pragma unroll
  for (int i = 0; i < 4; ++i)
#pragma unroll
    for (int j = 0; j < 4; ++j) acc[i][j] = (f32x4){0.f, 0.f, 0.f, 0.f};

  const int lin = tid * 8;                 // LDS slot (halfs), 16 B per thread
  const int lrow = lin >> 5;               // 0..63
  const int lblk = (lin >> 3) & 3;         // 16-B block within row
  const int csw = ((lblk ^ ((lrow >> 1) & 3)) << 3);   // XOR bank swizzle

  auto stage = [&](int k0, int kb) {
    if constexpr (EPI == 1) {
      if (k0 < 128) {
        const _Float16* gA = A0 + (size_t)(bm0 + lrow) * 128 + (k0 + csw);
        async16(gA, &sA[kb][lin]);
        async16(gA + (size_t)64 * 128, &sA[kb][lin + 2048]);
      } else {
        const _Float16* gA = A2 + (size_t)(bm0 + lrow) * 192 + (k0 - 128 + csw);
        async16(gA, &sA[kb][lin]);
        async16(gA + (size_t)64 * 192, &sA[kb][lin + 2048]);
      }
    } else {
      const _Float16* gA = A0 + (size_t)(bm0 + lrow) * Kd + (k0 + csw);
      async16(gA, &sA[kb][lin]);
      async16(gA + (size_t)64 * Kd, &sA[kb][lin + 2048]);
    }
    const _Float16* gB = B0 + (size_t)(bn0 + lrow) * Kd + (k0 + csw);
    async16(gB, &sB[kb][lin]);
    async16(gB + (size_t)64 * Kd, &sB[kb][lin + 2048]);
  };

  const int niter = (kend - kbeg) / 32;
  stage(kbeg, 0);
  if (niter > 1) stage(kbeg + 32, 1);

  for (int it = 0; it < niter; ++it) {
    if (it == niter - 1)
      __builtin_amdgcn_s_waitcnt(0x0F70);   // vmcnt(0)
    else
      __builtin_amdgcn_s_waitcnt(0x0F74);   // vmcnt(4)
    __builtin_amdgcn_s_barrier();
    asm volatile("" ::: "memory");
    const int kb = it & 1;
    half8 a0[4], b0[4];
#pragma unroll
    for (int i = 0; i < 4; ++i) {
      const int rA = wr + i * 16 + m16;
      a0[i] = *(const half8*)&sA[kb][rA * 32 + ((quad ^ ((rA >> 1) & 3)) << 3)];
    }
#pragma unroll
    for (int j = 0; j < 4; ++j) {
      const int rB = wc + j * 16 + m16;
      b0[j] = *(const half8*)&sB[kb][rB * 32 + ((quad ^ ((rB >> 1) & 3)) << 3)];
    }
#pragma unroll
    for (int i = 0; i < 4; ++i)
#pragma unroll
      for (int j = 0; j < 4; ++j)
        acc[i][j] = __builtin_amdgcn_mfma_f32_16x16x32_f16(a0[i], b0[j], acc[i][j], 0, 0, 0);
    asm volatile("" ::: "memory");
    __builtin_amdgcn_s_barrier();
    asm volatile("" ::: "memory");
    if (it + 2 < niter) stage(kbeg + (it + 2) * 32, kb);
  }

  // epilogues (C/D layout: col=lane&15, row=quad*4+reg)
  if constexpr (EPI == 1) {
#pragma unroll
    for (int i = 0; i < 4; ++i) {
      const int row0 = bm0 + wr + i * 16 + quad * 4;
#pragma unroll
      for (int j = 0; j < 4; j += 2) {
        const int colv = bn0 + wc + j * 16 + m16;
        const int jout = (colv >> 5) * 16 + m16;
#pragma unroll
        for (int r = 0; r < 4; ++r) {
          float val = acc[i][j][r];
          float g = acc[i][j + 1][r];
          float s = g / (1.f + __expf(-g));
          YH[(size_t)(row0 + r) * 2304 + kz * 192 + jout] = (_Float16)(val * s);
        }
      }
    }
  } else if constexpr (EPI == 2) {
    _Float16* zh = (_Float16*)Cb;
#pragma unroll
    for (int i = 0; i < 4; ++i) {
      const int row0 = bm0 + wr + i * 16 + quad * 4;
#pragma unroll
      for (int j = 0; j < 4; ++j) {
        const int col = bn0 + wc + j * 16 + m16;
        if (col < 3072) {
#pragma unroll
          for (int r = 0; r < 4; ++r)
            QH[(size_t)(row0 + r) * QST_ + col] = (_Float16)acc[i][j][r];
        } else if (col < 3264) {
          const int jj = col - 3072;
#pragma unroll
          for (int r = 0; r < 4; ++r)
            YH[(size_t)(row0 + r) * 192 + jj] = (_Float16)acc[i][j][r];
        } else if (col >= 3328 && col < 3328 + ZC_) {
          const int wz = col - 3328;
#pragma unroll
          for (int r = 0; r < 4; ++r)
            zh[(size_t)(row0 + r) * ZC_ + wz] = (_Float16)acc[i][j][r];
        }
      }
    }
  } else {
#pragma unroll
    for (int i = 0; i < 4; ++i) {
      const int row0 = bm0 + wr + i * 16 + quad * 4;
#pragma unroll
      for (int j = 0; j < 4; ++j) {
        const int col = bn0 + wc + j * 16 + m16;
        if (col < Nact) {
#pragma unroll
          for (int r = 0; r < 4; ++r) {
            if (ATOMIC)
              atomicAdd(&Cb[(size_t)(row0 + r) * Nact + col], acc[i][j][r]);
            else
              Cb[(size_t)(row0 + r) * Nact + col] = acc[i][j][r];
          }
        }
      }
    }
  }
}

// ---------------------------------------------------------------------------
// Scan pass A with fused causal conv (sliding 4-tap window over fp16 z)
// ---------------------------------------------------------------------------
__global__ void pass_a_kernel(const _Float16* __restrict__ zp,
                              const float* __restrict__ ck,
                              const float* __restrict__ theta_tab,
                              const float* __restrict__ score_scale,
                              const float* __restrict__ tanh_scale,
                              const float* __restrict__ slopes_sp,
                              float* __restrict__ csums) {
  const int c = blockIdx.x, k = blockIdx.y, b = blockIdx.z;
  const int tid = threadIdx.x;
  const int m = tid & 3, h = tid >> 2;
  const int chk = k * H_ + h;
  const int chs = 768 + k;
  const float theta_v = theta_tab[chk * M_ + m];
  const float ts = tanh_scale[k], ss = score_scale[k], slope = slopes_sp[k];
  float ckv[4], cks[4];
#pragma unroll
  for (int w = 0; w < 4; ++w) { ckv[w] = ck[w * ZC_ + chk]; cks[w] = ck[w * ZC_ + chs]; }
  const int l0 = c * LC_;
  float zk3 = 0.f, zk2 = 0.f, zk1 = 0.f, zs3 = 0.f, zs2 = 0.f, zs1 = 0.f;
#pragma unroll
  for (int p = 0; p < 3; ++p) {
    int lp = l0 - 3 + p;
    if (lp >= 0) {
      size_t tp = (size_t)b * L_ + lp;
      float zk = (float)zp[tp * ZC_ + chk], zs = (float)zp[tp * ZC_ + chs];
      if (p == 0) { zk3 = zk; zs3 = zs; }
      else if (p == 1) { zk2 = zk; zs2 = zs; }
      else { zk1 = zk; zs1 = zs; }
    }
  }
  float sre = 0.f, sim = 0.f, dacc = 0.f;
  for (int ll = 0; ll < LC_; ++ll) {
    int l = l0 + ll;
    size_t t = (size_t)b * L_ + l;
    float zk0 = (float)zp[t * ZC_ + chk];
    float zs0 = (float)zp[t * ZC_ + chs];
    float kv = zk3 * ckv[0] + zk2 * ckv[1] + zk1 * ckv[2] + zk0 * ckv[3];
    float sraw = zs3 * cks[0] + zs2 * cks[1] + zs1 * cks[2] + zs0 * cks[3];
    zk3 = zk2; zk2 = zk1; zk1 = zk0;
    zs3 = zs2; zs2 = zs1; zs1 = zs0;
    float lp = fminf(fmaxf(ss * sraw, -20.f), 20.f);
    float pw = __expf(lp - slope * (float)(L_ - 1 - l));
    float ph = fast_tanh(ts * kv) * theta_v;
    float kvp = kv * pw;
    sre += kvp * __cosf(ph);
    sim += kvp * __sinf(ph);
    dacc += pw;
  }
  size_t base = (((size_t)b * K_ + k) * NC_ + c) * 513;
  if (tid == 0) csums[base] = dacc;
  csums[base + 1 + h * 4 + m] = sre;
  csums[base + 1 + 256 + h * 4 + m] = sim;
}

// ---------------------------------------------------------------------------
__global__ void pass_b_kernel(const float* __restrict__ csums,
                              float* __restrict__ cpre) {
  int bk = blockIdx.y;
  int comp = blockIdx.x * 64 + threadIdx.x;
  if (comp >= 513) return;
  float run = 0.f;
  size_t base = (size_t)bk * NC_ * 513 + comp;
  for (int c = 0; c < NC_; ++c) {
    cpre[base + (size_t)c * 513] = run;
    run += csums[base + (size_t)c * 513];
  }
}

// ---------------------------------------------------------------------------
// Scan pass C: fused conv replay, contract with fp16 q, apply ns*gate,
// write fp16 into asp2[k][t][0:128] (128-stride)
// ---------------------------------------------------------------------------
__global__ void pass_c_kernel(const _Float16* __restrict__ zp,
                              const float* __restrict__ ck,
                              const _Float16* __restrict__ qh,
                              const float* __restrict__ theta_tab,
                              const float* __restrict__ w_tab,
                              const float* __restrict__ score_scale,
                              const float* __restrict__ tanh_scale,
                              const float* __restrict__ slopes_sp,
                              const float* __restrict__ cpre,
                              const float* __restrict__ gatelin,
                              const float* __restrict__ gate_b,
                              const float* __restrict__ ns,
                              _Float16* __restrict__ asp) {
  const int c = blockIdx.x, k = blockIdx.y, b = blockIdx.z;
  const int tid = threadIdx.x;
  const int m = tid & 3, h = tid >> 2;
  const int chk = k * H_ + h;
  const int chs = 768 + k;
  size_t base = (((size_t)b * K_ + k) * NC_ + c) * 513;
  float den = cpre[base];
  float sre = cpre[base + 1 + h * 4 + m];
  float sim = cpre[base + 1 + 256 + h * 4 + m];
  const float theta_v = theta_tab[chk * M_ + m];
  const float w = w_tab[chk * M_ + m];
  const float ts = tanh_scale[k], ss = score_scale[k], slope = slopes_sp[k];
  const float nsv = ns[chk];
  const float gb = gate_b[k];
  const int kq = k >> 1;   // NREP = 2
  float ckv[4], cks[4];
#pragma unroll
  for (int ww = 0; ww < 4; ++ww) { ckv[ww] = ck[ww * ZC_ + chk]; cks[ww] = ck[ww * ZC_ + chs]; }
  const int l0 = c * LC_;
  float zk3 = 0.f, zk2 = 0.f, zk1 = 0.f, zs3 = 0.f, zs2 = 0.f, zs1 = 0.f;
#pragma unroll
  for (int p = 0; p < 3; ++p) {
    int lp = l0 - 3 + p;
    if (lp >= 0) {
      size_t tp = (size_t)b * L_ + lp;
      float zk = (float)zp[tp * ZC_ + chk], zs = (float)zp[tp * ZC_ + chs];
      if (p == 0) { zk3 = zk; zs3 = zs; }
      else if (p == 1) { zk2 = zk; zs2 = zs; }
      else { zk1 = zk; zs1 = zs; }
    }
  }
  const int qidx = ((kq * H_ + h) * M_ + m) * 2;
  for (int ll = 0; ll < LC_; ++ll) {
    int l = l0 + ll;
    size_t t = (size_t)b * L_ + l;
    float zk0 = (float)zp[t * ZC_ + chk];
    float zs0 = (float)zp[t * ZC_ + chs];
    float kv = zk3 * ckv[0] + zk2 * ckv[1] + zk1 * ckv[2] + zk0 * ckv[3];
    float sraw = zs3 * cks[0] + zs2 * cks[1] + zs1 * cks[2] + zs0 * cks[3];
    zk3 = zk2; zk2 = zk1; zk1 = zk0;
    zs3 = zs2; zs2 = zs1; zs1 = zs0;
    float lp = fminf(fmaxf(ss * sraw, -20.f), 20.f);
    float pw = __expf(lp - slope * (float)(L_ - 1 - l));
    float ph = fast_tanh(ts * kv) * theta_v;
    float kvp = kv * pw;
    sre += kvp * __cosf(ph);
    sim += kvp * __sinf(ph);
    den += pw;
    float inv = 1.f / fmaxf(den, 1e-4f);
    float s_re = sre * inv, s_im = sim * inv;
    size_t qb = t * QST_ + qidx;
    float qr = (float)qh[qb], qi = (float)qh[qb + 1];
    float tr = (s_re * qr + s_im * qi) * w;
    float ti = (s_im * qr - s_re * qi) * w;
    tr += __shfl_xor(tr, 1); tr += __shfl_xor(tr, 2);
    ti += __shfl_xor(ti, 1); ti += __shfl_xor(ti, 2);
    if (m == 0) {
      float g = 1.f / (1.f + __expf(-(gatelin[t * K_ + k] + gb))) * nsv;
      size_t ab = ((size_t)k * NTOK_ + t) * 128;
      asp[ab + h] = (_Float16)(tr * g);
      asp[ab + 64 + h] = (_Float16)(ti * g);
    }
  }
}

// ---------------------------------------------------------------------------
extern "C" void kernel_launch(void* const* d_in, const int* in_sizes, int n_in,
                              void* d_out, int out_size, void* d_ws, size_t ws_size,
                              hipStream_t stream) {
  const float* x            = (const float*)d_in[0];
  const float* W_mem        = (const float*)d_in[1];
  const float* conv_k       = (const float*)d_in[2];
  const float* W_q          = (const float*)d_in[3];
  const float* theta_d_raw  = (const float*)d_in[4];
  const float* decay_slopes = (const float*)d_in[5];
  const float* score_scale  = (const float*)d_in[6];
  const float* tanh_scale   = (const float*)d_in[7];
  const float* W_re         = (const float*)d_in[8];
  const float* W_im         = (const float*)d_in[9];
  const float* norm_scale   = (const float*)d_in[10];
  const float* gate_W       = (const float*)d_in[11];
  const float* gate_b       = (const float*)d_in[12];
  const float* skip_down_W  = (const float*)d_in[13];
  const float* skip_up_W    = (const float*)d_in[14];
  const float* highway_scale= (const float*)d_in[15];
  const float* out_W        = (const float*)d_in[16];
  float* out = (float*)d_out;
  float* ws = (float*)d_ws;

  // ---- f32 region ----
  float* theta_tab = ws;                                  // 3072
  float* w_tab     = theta_tab + 3072;                    // 3072
  float* slopes_sp = w_tab + 3072;                        // 16
  float* gatelin   = slopes_sp + 16;                      // 49,152
  float* csums     = gatelin + (size_t)NTOK_ * K_;        // 787,968
  float* cpre      = csums + (size_t)B_ * K_ * NC_ * 513; // 787,968
  float* f32_end   = cpre + (size_t)B_ * K_ * NC_ * 513;

  // ---- fp16 region ----
  _Float16* fp = (_Float16*)f32_end;
  _Float16* z_h    = fp;                fp += (size_t)NTOK_ * ZC_;   // fp16 z
  _Float16* q_h    = fp;                fp += (size_t)NTOK_ * QST_;
  _Float16* y_h    = fp;                fp += (size_t)NTOK_ * 2304;
  _Float16* x_h    = fp;                fp += (size_t)NTOK_ * D_;
  _Float16* xpb_h  = fp;                fp += (size_t)XPN_ * 768;
  _Float16* outw_h = fp;                fp += (size_t)768 * 2304;
  _Float16* asp2_h = fp;                fp += (size_t)K_ * NTOK_ * 128;
  _Float16* bsp_h  = fp;                fp += (size_t)K_ * 384 * 320;
  _Float16* lat_h  = fp;                fp += (size_t)NTOK_ * 192;

  // merged prep: weight conversions + out-zero + x->fp16 + precomp
  prep_kernel<<<30915, 256, 0, stream>>>(x, out, theta_d_raw, decay_slopes,
                                         theta_tab, w_tab, slopes_sp,
                                         W_mem, W_q, skip_down_W, out_W, W_re, W_im,
                                         skip_up_W, highway_scale,
                                         x_h, xpb_h, outw_h, bsp_h);

  // merged x-projection: q (fp16) + lat (fp16) + z (fp16) in one dispatch,
  // XCD-swizzled 1D grid (33 x 32 x 1)
  mfma_gemm_kernel<0, 2><<<1056, 256, 0, stream>>>(x_h, xpb_h, (float*)z_h,
                                                   768, XPN_, 0, 0, 0,
                                                   nullptr, lat_h, q_h, 32, 1);
  // gatelin = x @ gate_W
  gate_kernel<<<NTOK_ / 4, 256, 0, stream>>>(x, gate_W, gatelin);

  // chunked scan with fused causal conv (fp16 z)
  pass_a_kernel<<<dim3(NC_, K_, B_), 256, 0, stream>>>(z_h, conv_k, theta_tab, score_scale,
                                                       tanh_scale, slopes_sp, csums);
  pass_b_kernel<<<dim3(9, B_ * K_), 64, 0, stream>>>(csums, cpre);
  pass_c_kernel<<<dim3(NC_, K_, B_), 256, 0, stream>>>(z_h, conv_k, q_h, theta_tab, w_tab,
                                                       score_scale, tanh_scale, slopes_sp, cpre,
                                                       gatelin, gate_b, norm_scale, asp2_h);

  // batched spec GEMM (A = [asp2 per-k | lat_h shared], hs folded into bsp)
  // with fused SiLU -> y_h fp16, XCD-swizzled (3 x 32 x 12)
  mfma_gemm_kernel<0, 1><<<1152, 256, 0, stream>>>(asp2_h, bsp_h, nullptr,
                                                   320, 384,
                                                   (long)NTOK_ * 128, 384L * 320, 0,
                                                   lat_h, y_h, nullptr, 32, 12);
  // out += y @ out_W  (split-K=4, atomic, XCD-swizzled 6 x 32 x 4)
  mfma_gemm_kernel<1, 0><<<768, 256, 0, stream>>>(y_h, outw_h, out,
                                                  2304, 768, 0, 0, 0,
                                                  nullptr, nullptr, nullptr, 32, 4);
}